// Round 5
// baseline (2234.514 us; speedup 1.0000x reference)
//
#include <hip/hip_runtime.h>

#define T_STEPS 2048

typedef float f2 __attribute__((ext_vector_type(2)));

__device__ __forceinline__ float fast_rcp(float x) { return __builtin_amdgcn_rcpf(x); }

// force a value to stay materialized in a VGPR (blocks rematerialization of
// the load that produced it — the RA must keep it live instead of re-loading)
__device__ __forceinline__ void pin(float& x) { asm volatile("" : "+v"(x)); }

// sigmoid family: sigmoid(x): zm=1,sm=1,sa=0 ; tanh(x)=2*sigmoid(2x)-1: zm=2,sm=2,sa=-1
__device__ __forceinline__ float gate_act(float x, float zm, float sm, float sa) {
    float e = __expf(-x * zm);
    return fmaf(fast_rcp(1.0f + e), sm, sa);
}

__device__ __forceinline__ float tanh_f(float c) {
    float e = __expf(-2.0f * c);
    return fmaf(2.0f, fast_rcp(1.0f + e), -1.0f);
}

__device__ __forceinline__ void loadx4(float (&dst)[4], const float* __restrict__ x_r,
                                       const float* __restrict__ x_t,
                                       size_t xrb, size_t xtb, int l) {
#pragma unroll
    for (int u = 0; u < 4; ++u) {
        int v = l + 16 * u;
        dst[u] = (v < 47) ? x_r[xrb + v] : ((v < 49) ? x_t[xtb + (v - 47)] : 0.0f);
    }
}

__global__ __launch_bounds__(448, 1) void adrnn_fused(
    const float* __restrict__ x_r, const float* __restrict__ x_t,
    const float* __restrict__ rWih0, const float* __restrict__ rWhh0,
    const float* __restrict__ rbih0, const float* __restrict__ rbhh0,
    const float* __restrict__ rWih1, const float* __restrict__ rWhh1,
    const float* __restrict__ rbih1, const float* __restrict__ rbhh1,
    const float* __restrict__ tWih0, const float* __restrict__ tWhh0,
    const float* __restrict__ tbih0, const float* __restrict__ tbhh0,
    const float* __restrict__ tWih1, const float* __restrict__ tWhh1,
    const float* __restrict__ tbih1, const float* __restrict__ tbhh1,
    float* __restrict__ r_out, float* __restrict__ t_out)
{
    // ping-pong input vectors; iter i reads buf[i&1], writes buf[(i+1)&1]
    __shared__ __align__(16) float in0[2][96];   // [x_r(47)|x_t(2)|hr0(47)]
    __shared__ __align__(16) float in1[2][96];   // [hr0(47)|pad|hr1(47)|pad]
    __shared__ __align__(16) float ring[4][49];  // x(t) history for t-RNN (lag 2)

    const int tid = threadIdx.x;
    const int b = blockIdx.x;
    const size_t xr_base = (size_t)b * T_STEPS * 47;
    const size_t xt_base = (size_t)b * T_STEPS * 2;

    if (tid < 96) {
        in1[0][tid] = 0.0f; in1[1][tid] = 0.0f;
        if (tid >= 49) { in0[0][tid] = 0.0f; in0[1][tid] = 0.0f; }
    }

    if (tid < 384) {
        // ===== A group (waves 0-2): layer-0 step i. B group (waves 3-5): layer-1 step i-1.
        // lane (jj, q): quarter-q partial dot (24 elems) for ALL 4 gates of unit jj.
        const bool isA = (tid < 192);
        const int t0 = isA ? tid : tid - 192;
        const int jj = t0 >> 2, q = t0 & 3;
        const bool act_lane = (jj < 47);

        f2 w[4][12];
#pragma unroll
        for (int g = 0; g < 4; ++g)
#pragma unroll
            for (int u = 0; u < 12; ++u) w[g][u] = f2{0.0f, 0.0f};
        float bias = 0.0f;
        if (act_lane) {
            if (isA) {
#pragma unroll
                for (int g = 0; g < 4; ++g) {
                    const int rg = g * 47 + jj;
#pragma unroll
                    for (int u = 0; u < 12; ++u) {
                        int c0 = 24 * q + 2 * u, c1 = c0 + 1;
                        float w0 = (c0 < 49) ? rWih0[rg * 49 + c0] : rWhh0[rg * 47 + (c0 - 49)];
                        float w1 = (c1 < 49) ? rWih0[rg * 49 + c1] : rWhh0[rg * 47 + (c1 - 49)];
                        w[g][u] = f2{w0, w1};
                    }
                }
                bias = rbih0[q * 47 + jj] + rbhh0[q * 47 + jj];
            } else {
#pragma unroll
                for (int g = 0; g < 4; ++g) {
                    const int rg = g * 47 + jj;
#pragma unroll
                    for (int u = 0; u < 12; ++u) {
                        int c0 = 24 * q + 2 * u, c1 = c0 + 1;
                        float w0 = 0.0f, w1 = 0.0f;
                        if (c0 < 47) w0 = rWih1[rg * 47 + c0];
                        else if (c0 >= 48 && c0 < 95) w0 = rWhh1[rg * 47 + (c0 - 48)];
                        if (c1 < 47) w1 = rWih1[rg * 47 + c1];
                        else if (c1 >= 48 && c1 < 95) w1 = rWhh1[rg * 47 + (c1 - 48)];
                        w[g][u] = f2{w0, w1};
                    }
                }
                bias = rbih1[q * 47 + jj] + rbhh1[q * 47 + jj];
            }
        }
        // PIN the weights into VGPRs: make the loads non-rematerializable so the
        // register allocator cannot sink them back into the 2050-iteration loop.
#pragma unroll
        for (int g = 0; g < 4; ++g)
#pragma unroll
            for (int u = 0; u < 12; ++u) {
                float lo = w[g][u].x, hi = w[g][u].y;
                pin(lo); pin(hi);
                w[g][u] = f2{lo, hi};
            }
        pin(bias);

        // this lane activates gate q (0=i,1=f,2=g,3=o)
        const float zm = (q == 2) ? 2.0f : 1.0f;
        const float sm = (q == 2) ? 2.0f : 1.0f;
        const float sa = (q == 2) ? -1.0f : 0.0f;
        const bool wr = (q == 0) && act_lane;
        float c = 0.0f;

        __syncthreads();   // pre-loop: all init/stage writes visible

        for (int i = 0; i <= T_STEPS + 1; ++i) {
            const int cur = i & 1, nxt = cur ^ 1;
            const bool on = isA ? (i < T_STEPS) : (i >= 1 && i <= T_STEPS);
            if (on) {
                const float4* v4 = reinterpret_cast<const float4*>(isA ? in0[cur] : in1[cur]) + 6 * q;
                f2 a00 = {0,0}, a01 = {0,0}, a10 = {0,0}, a11 = {0,0};
                f2 a20 = {0,0}, a21 = {0,0}, a30 = {0,0}, a31 = {0,0};
#pragma unroll
                for (int u = 0; u < 6; ++u) {
                    float4 v = v4[u];
                    f2 lo = f2{v.x, v.y}, hi = f2{v.z, v.w};
                    a00 = __builtin_elementwise_fma(w[0][2*u],   lo, a00);
                    a01 = __builtin_elementwise_fma(w[0][2*u+1], hi, a01);
                    a10 = __builtin_elementwise_fma(w[1][2*u],   lo, a10);
                    a11 = __builtin_elementwise_fma(w[1][2*u+1], hi, a11);
                    a20 = __builtin_elementwise_fma(w[2][2*u],   lo, a20);
                    a21 = __builtin_elementwise_fma(w[2][2*u+1], hi, a21);
                    a30 = __builtin_elementwise_fma(w[3][2*u],   lo, a30);
                    a31 = __builtin_elementwise_fma(w[3][2*u+1], hi, a31);
                }
                f2 s0 = a00 + a01, s1 = a10 + a11, s2 = a20 + a21, s3 = a30 + a31;
                float P0 = s0.x + s0.y, P1 = s1.x + s1.y, P2 = s2.x + s2.y, P3 = s3.x + s3.y;
                // butterfly across the 4 quarter-lanes: full pre-acts for all 4 gates
                P0 += __shfl_xor(P0, 1, 64); P1 += __shfl_xor(P1, 1, 64);
                P2 += __shfl_xor(P2, 1, 64); P3 += __shfl_xor(P3, 1, 64);
                P0 += __shfl_xor(P0, 2, 64); P1 += __shfl_xor(P1, 2, 64);
                P2 += __shfl_xor(P2, 2, 64); P3 += __shfl_xor(P3, 2, 64);
                float pre = (q & 2) ? ((q & 1) ? P3 : P2) : ((q & 1) ? P1 : P0);
                pre += bias;
                float av = gate_act(pre, zm, sm, sa);
                // gather i,f,g,o at the q==0 lane
                float fv = __shfl_xor(av, 1, 64);
                float gv = __shfl_xor(av, 2, 64);
                float ov = __shfl_xor(av, 3, 64);
                if (wr) {
                    c = fmaf(fv, c, av * gv);
                    float h = ov * tanh_f(c);
                    if (isA) {
                        in0[nxt][49 + jj] = h;
                        in1[nxt][jj] = h;
                    } else {
                        in1[nxt][48 + jj] = h;
                        r_out[((size_t)b * T_STEPS + (i - 1)) * 47 + jj] = h;
                    }
                }
            }
            __syncthreads();
        }
    } else {
        // ===== T wave (wave 6): t-RNN step i-2 + x staging =====
        const int l = tid - 384;
        const int gt = l >> 3, p = l & 7;      // t0: 8 lanes per gate
        float wT[12];
#pragma unroll
        for (int u = 0; u < 12; ++u) wT[u] = tWih0[gt * 96 + p * 12 + u];
        float bT0 = tbih0[gt] + tbhh0[gt];
        float wh00 = tWhh0[gt * 2 + 0], wh01 = tWhh0[gt * 2 + 1];
        const int g1 = l & 7;                  // t1: 1 lane per gate (replicated x8)
        float wi10 = tWih1[g1 * 2 + 0], wi11 = tWih1[g1 * 2 + 1];
        float wh10 = tWhh1[g1 * 2 + 0], wh11 = tWhh1[g1 * 2 + 1];
        float bT1 = tbih1[g1] + tbhh1[g1];
#pragma unroll
        for (int u = 0; u < 12; ++u) pin(wT[u]);
        pin(bT0); pin(wh00); pin(wh01);
        pin(wi10); pin(wi11); pin(wh10); pin(wh11); pin(bT1);
        const bool isg0 = ((gt >> 1) == 2);
        const float zm0 = isg0 ? 2.f : 1.f, sm0 = isg0 ? 2.f : 1.f, sa0 = isg0 ? -1.f : 0.f;
        const bool isg1 = ((g1 >> 1) == 2);
        const float zm1 = isg1 ? 2.f : 1.f, sm1 = isg1 ? 2.f : 1.f, sa1 = isg1 ? -1.f : 0.f;
        float ht00 = 0.f, ht01 = 0.f, ct00 = 0.f, ct01 = 0.f;
        float ht10 = 0.f, ht11 = 0.f, ct10 = 0.f, ct11 = 0.f;

        // depth-3 register prefetch pipeline: entering iter i, xa=x(i+1), xb=x(i+2), xc=x(i+3)
        float xa[4] = {0,0,0,0}, xb[4] = {0,0,0,0}, xc[4] = {0,0,0,0};
        if (l < 16) {
            float x0[4];
            loadx4(x0, x_r, x_t, xr_base, xt_base, l);
#pragma unroll
            for (int u = 0; u < 4; ++u) {
                int v = l + 16 * u;
                if (v < 49) { in0[0][v] = x0[u]; ring[0][v] = x0[u]; }
            }
            loadx4(xa, x_r, x_t, xr_base + 47,     xt_base + 2,     l);
            loadx4(xb, x_r, x_t, xr_base + 2 * 47, xt_base + 2 * 2, l);
            loadx4(xc, x_r, x_t, xr_base + 3 * 47, xt_base + 3 * 2, l);
        }
        __syncthreads();   // pre-loop

        for (int i = 0; i <= T_STEPS + 1; ++i) {
            const int cur = i & 1, nxt = cur ^ 1;
            if (i >= 2) {
                // t0 gates, step tau=i-2; input = [x(tau)(49) | hr1(tau)(47)]
                const float* xcr = ring[(i - 2) & 3];
                const float* h1c = in1[cur];
                float acc = 0.0f;
#pragma unroll
                for (int u = 0; u < 12; ++u) {
                    int idx = p * 12 + u;
                    const float* src = (idx < 49) ? (xcr + idx) : (h1c + (idx - 1));
                    acc = fmaf(wT[u], *src, acc);
                }
                acc += __shfl_xor(acc, 1, 64);
                acc += __shfl_xor(acc, 2, 64);
                acc += __shfl_xor(acc, 4, 64);
                float pre0 = acc + bT0 + wh00 * ht00 + wh01 * ht01;
                float act0t = gate_act(pre0, zm0, sm0, sa0);
                float iv0 = __shfl(act0t, 0, 64),  iv1 = __shfl(act0t, 8, 64);
                float fv0 = __shfl(act0t, 16, 64), fv1 = __shfl(act0t, 24, 64);
                float gv0 = __shfl(act0t, 32, 64), gv1 = __shfl(act0t, 40, 64);
                float ov0 = __shfl(act0t, 48, 64), ov1 = __shfl(act0t, 56, 64);
                ct00 = fmaf(fv0, ct00, iv0 * gv0);
                ct01 = fmaf(fv1, ct01, iv1 * gv1);
                ht00 = ov0 * tanh_f(ct00);
                ht01 = ov1 * tanh_f(ct01);
                float pre1 = bT1 + wi10 * ht00 + wi11 * ht01 + wh10 * ht10 + wh11 * ht11;
                float a1v = gate_act(pre1, zm1, sm1, sa1);
                float ji0 = __shfl(a1v, 0, 64), ji1 = __shfl(a1v, 1, 64);
                float jf0 = __shfl(a1v, 2, 64), jf1 = __shfl(a1v, 3, 64);
                float jg0 = __shfl(a1v, 4, 64), jg1 = __shfl(a1v, 5, 64);
                float jo0 = __shfl(a1v, 6, 64), jo1 = __shfl(a1v, 7, 64);
                ct10 = fmaf(jf0, ct10, ji0 * jg0);
                ct11 = fmaf(jf1, ct11, ji1 * jg1);
                ht10 = jo0 * tanh_f(ct10);
                ht11 = jo1 * tanh_f(ct11);
                if (l < 2) t_out[((size_t)b * T_STEPS + (i - 2)) * 2 + l] = (l == 0) ? ht10 : ht11;
            }
            if (l < 16) {
                const int tw = i + 1;
                if (tw < T_STEPS) {
#pragma unroll
                    for (int u = 0; u < 4; ++u) {
                        int v = l + 16 * u;
                        if (v < 49) { in0[nxt][v] = xa[u]; ring[tw & 3][v] = xa[u]; }
                    }
                }
#pragma unroll
                for (int u = 0; u < 4; ++u) { xa[u] = xb[u]; xb[u] = xc[u]; }
                int tl = i + 4;
                if (tl > T_STEPS - 1) tl = T_STEPS - 1;
                loadx4(xc, x_r, x_t, xr_base + (size_t)tl * 47, xt_base + (size_t)tl * 2, l);
            }
            __syncthreads();
        }
    }
}

extern "C" void kernel_launch(void* const* d_in, const int* in_sizes, int n_in,
                              void* d_out, int out_size, void* d_ws, size_t ws_size,
                              hipStream_t stream) {
    const float* x_r   = (const float*)d_in[0];
    const float* x_t   = (const float*)d_in[1];
    const float* rWih0 = (const float*)d_in[2];
    const float* rWhh0 = (const float*)d_in[3];
    const float* rbih0 = (const float*)d_in[4];
    const float* rbhh0 = (const float*)d_in[5];
    const float* rWih1 = (const float*)d_in[6];
    const float* rWhh1 = (const float*)d_in[7];
    const float* rbih1 = (const float*)d_in[8];
    const float* rbhh1 = (const float*)d_in[9];
    const float* tWih0 = (const float*)d_in[10];
    const float* tWhh0 = (const float*)d_in[11];
    const float* tbih0 = (const float*)d_in[12];
    const float* tbhh0 = (const float*)d_in[13];
    const float* tWih1 = (const float*)d_in[14];
    const float* tWhh1 = (const float*)d_in[15];
    const float* tbih1 = (const float*)d_in[16];
    const float* tbhh1 = (const float*)d_in[17];

    float* r_out = (float*)d_out;
    float* t_out = r_out + (size_t)256 * T_STEPS * 47;

    hipLaunchKernelGGL(adrnn_fused, dim3(256), dim3(448), 0, stream,
                       x_r, x_t, rWih0, rWhh0, rbih0, rbhh0, rWih1, rWhh1, rbih1, rbhh1,
                       tWih0, tWhh0, tbih0, tbhh0, tWih1, tWhh1, tbih1, tbhh1,
                       r_out, t_out);
}

// Round 6
// 1877.866 us; speedup vs baseline: 1.1899x; 1.1899x over previous
//
#include <hip/hip_runtime.h>

#define T_STEPS 2048

typedef float f2 __attribute__((ext_vector_type(2)));

__device__ __forceinline__ float fast_rcp(float x) { return __builtin_amdgcn_rcpf(x); }

// sigmoid(x): zm=1,sm=1,sa=0 ; tanh(x)=2*sigmoid(2x)-1: zm=2,sm=2,sa=-1
__device__ __forceinline__ float gate_act(float x, float zm, float sm, float sa) {
    float e = __expf(-x * zm);
    return fmaf(fast_rcp(1.0f + e), sm, sa);
}

__device__ __forceinline__ float tanh_f(float c) {
    float e = __expf(-2.0f * c);
    return fmaf(2.0f, fast_rcp(1.0f + e), -1.0f);
}

// DPP quad_perm cross-lane (register-file permute, ~4cy; replaces ds_bpermute ~100cy)
#define DPP_XOR1 0xB1   // quad_perm [1,0,3,2]
#define DPP_XOR2 0x4E   // quad_perm [2,3,0,1]
#define DPP_XOR3 0x1B   // quad_perm [3,2,1,0]

template<int CTRL>
__device__ __forceinline__ float dppf(float x) {
    int r = __builtin_amdgcn_update_dpp(0, __builtin_bit_cast(int, x), CTRL, 0xF, 0xF, true);
    return __builtin_bit_cast(float, r);
}

__device__ __forceinline__ float rlane(float x, int lane) {
    return __builtin_bit_cast(float, __builtin_amdgcn_readlane(__builtin_bit_cast(int, x), lane));
}

__device__ __forceinline__ void loadx4(float (&dst)[4], const float* __restrict__ x_r,
                                       const float* __restrict__ x_t,
                                       size_t xrb, size_t xtb, int l) {
#pragma unroll
    for (int u = 0; u < 4; ++u) {
        int v = l + 16 * u;
        dst[u] = (v < 47) ? x_r[xrb + v] : ((v < 49) ? x_t[xtb + (v - 47)] : 0.0f);
    }
}

__global__ __launch_bounds__(448, 1) void adrnn_fused(
    const float* __restrict__ x_r, const float* __restrict__ x_t,
    const float* __restrict__ rWih0, const float* __restrict__ rWhh0,
    const float* __restrict__ rbih0, const float* __restrict__ rbhh0,
    const float* __restrict__ rWih1, const float* __restrict__ rWhh1,
    const float* __restrict__ rbih1, const float* __restrict__ rbhh1,
    const float* __restrict__ tWih0, const float* __restrict__ tWhh0,
    const float* __restrict__ tbih0, const float* __restrict__ tbhh0,
    const float* __restrict__ tWih1, const float* __restrict__ tWhh1,
    const float* __restrict__ tbih1, const float* __restrict__ tbhh1,
    float* __restrict__ r_out, float* __restrict__ t_out)
{
    // ping-pong input vectors; iter i reads buf[i&1], writes buf[(i+1)&1]
    __shared__ __align__(16) float in0[2][96];    // [x_r(47)|x_t(2)|hr0(47)]
    __shared__ __align__(16) float in1[2][96];    // [hr0(47)|pad|hr1(47)|pad]
    __shared__ __align__(16) float tring[4][96];  // slot tau&3: [x(tau)(49)|hr1(tau)(47)]

    const int tid = threadIdx.x;
    const int b = blockIdx.x;
    const size_t xr_base = (size_t)b * T_STEPS * 47;
    const size_t xt_base = (size_t)b * T_STEPS * 2;

    if (tid < 96) {
        in1[0][tid] = 0.0f; in1[1][tid] = 0.0f;
        if (tid >= 49) { in0[0][tid] = 0.0f; in0[1][tid] = 0.0f; }
    }

    if (tid < 384) {
        // ===== A group (waves 0-2): layer-0 step i. B group (waves 3-5): layer-1 step i-1.
        // lane (jj, q): quarter-q partial dot (24 elems) for ALL 4 gates of unit jj.
        const bool isA = (tid < 192);
        const int t0 = isA ? tid : tid - 192;
        const int jj = t0 >> 2, q = t0 & 3;
        const bool act_lane = (jj < 47);

        f2 w[4][12];
#pragma unroll
        for (int g = 0; g < 4; ++g)
#pragma unroll
            for (int u = 0; u < 12; ++u) w[g][u] = f2{0.0f, 0.0f};
        float bias = 0.0f;
        if (act_lane) {
            if (isA) {
#pragma unroll
                for (int g = 0; g < 4; ++g) {
                    const int rg = g * 47 + jj;
#pragma unroll
                    for (int u = 0; u < 12; ++u) {
                        int c0 = 24 * q + 2 * u, c1 = c0 + 1;
                        float w0 = (c0 < 49) ? rWih0[rg * 49 + c0] : rWhh0[rg * 47 + (c0 - 49)];
                        float w1 = (c1 < 49) ? rWih0[rg * 49 + c1] : rWhh0[rg * 47 + (c1 - 49)];
                        w[g][u] = f2{w0, w1};
                    }
                }
                bias = rbih0[q * 47 + jj] + rbhh0[q * 47 + jj];
            } else {
#pragma unroll
                for (int g = 0; g < 4; ++g) {
                    const int rg = g * 47 + jj;
#pragma unroll
                    for (int u = 0; u < 12; ++u) {
                        int c0 = 24 * q + 2 * u, c1 = c0 + 1;
                        float w0 = 0.0f, w1 = 0.0f;
                        if (c0 < 47) w0 = rWih1[rg * 47 + c0];
                        else if (c0 >= 48 && c0 < 95) w0 = rWhh1[rg * 47 + (c0 - 48)];
                        if (c1 < 47) w1 = rWih1[rg * 47 + c1];
                        else if (c1 >= 48 && c1 < 95) w1 = rWhh1[rg * 47 + (c1 - 48)];
                        w[g][u] = f2{w0, w1};
                    }
                }
                bias = rbih1[q * 47 + jj] + rbhh1[q * 47 + jj];
            }
        }
        // this lane activates gate q (0=i,1=f,2=g,3=o)
        const float zm = (q == 2) ? 2.0f : 1.0f;
        const float sm = (q == 2) ? 2.0f : 1.0f;
        const float sa = (q == 2) ? -1.0f : 0.0f;
        const bool wr = (q == 0) && act_lane;
        float c = 0.0f;

        __syncthreads();   // pre-loop: all init/stage writes visible

        for (int i = 0; i <= T_STEPS + 1; ++i) {
            const int cur = i & 1, nxt = cur ^ 1;
            const bool on = isA ? (i < T_STEPS) : (i >= 1 && i <= T_STEPS);
            if (on) {
                const float4* v4 = reinterpret_cast<const float4*>(isA ? in0[cur] : in1[cur]) + 6 * q;
                f2 a00 = {0,0}, a01 = {0,0}, a10 = {0,0}, a11 = {0,0};
                f2 a20 = {0,0}, a21 = {0,0}, a30 = {0,0}, a31 = {0,0};
#pragma unroll
                for (int u = 0; u < 6; ++u) {
                    float4 v = v4[u];
                    f2 lo = f2{v.x, v.y}, hi = f2{v.z, v.w};
                    a00 = __builtin_elementwise_fma(w[0][2*u],   lo, a00);
                    a01 = __builtin_elementwise_fma(w[0][2*u+1], hi, a01);
                    a10 = __builtin_elementwise_fma(w[1][2*u],   lo, a10);
                    a11 = __builtin_elementwise_fma(w[1][2*u+1], hi, a11);
                    a20 = __builtin_elementwise_fma(w[2][2*u],   lo, a20);
                    a21 = __builtin_elementwise_fma(w[2][2*u+1], hi, a21);
                    a30 = __builtin_elementwise_fma(w[3][2*u],   lo, a30);
                    a31 = __builtin_elementwise_fma(w[3][2*u+1], hi, a31);
                }
                f2 s0 = a00 + a01, s1 = a10 + a11, s2 = a20 + a21, s3 = a30 + a31;
                float P0 = s0.x + s0.y, P1 = s1.x + s1.y, P2 = s2.x + s2.y, P3 = s3.x + s3.y;
                // DPP butterfly across the 4 quarter-lanes (register permute, no LDS pipe)
                P0 += dppf<DPP_XOR1>(P0); P1 += dppf<DPP_XOR1>(P1);
                P2 += dppf<DPP_XOR1>(P2); P3 += dppf<DPP_XOR1>(P3);
                P0 += dppf<DPP_XOR2>(P0); P1 += dppf<DPP_XOR2>(P1);
                P2 += dppf<DPP_XOR2>(P2); P3 += dppf<DPP_XOR2>(P3);
                float pre = (q & 2) ? ((q & 1) ? P3 : P2) : ((q & 1) ? P1 : P0);
                pre += bias;
                float av = gate_act(pre, zm, sm, sa);
                // gather i,f,g,o within the quad via DPP
                float fv = dppf<DPP_XOR1>(av);
                float gv = dppf<DPP_XOR2>(av);
                float ov = dppf<DPP_XOR3>(av);
                if (wr) {
                    c = fmaf(fv, c, av * gv);
                    float h = ov * tanh_f(c);
                    if (isA) {
                        in0[nxt][49 + jj] = h;
                        in1[nxt][jj] = h;
                    } else {
                        in1[nxt][48 + jj] = h;
                        tring[(i - 1) & 3][49 + jj] = h;   // hr1(i-1) for the t-RNN
                        r_out[((size_t)b * T_STEPS + (i - 1)) * 47 + jj] = h;
                    }
                }
            }
            __syncthreads();
        }
    } else {
        // ===== T wave (wave 6): t-RNN step i-2 (zero bpermutes) + x staging =====
        const int l = tid - 384;
        const int G = (l >> 2) & 7;            // gate index: type*2+unit (lanes 32-63 replicate)
        const int p = l & 3;                   // quarter of the 96-elem input
        // layer-0 weights: quarter-p slice (24 elems) of row G
        f2 wT[12];
#pragma unroll
        for (int u = 0; u < 12; ++u)
            wT[u] = f2{tWih0[G * 96 + p * 24 + 2 * u], tWih0[G * 96 + p * 24 + 2 * u + 1]};
        const float bT0 = tbih0[G] + tbhh0[G];
        const float wh00 = tWhh0[G * 2 + 0], wh01 = tWhh0[G * 2 + 1];
        const float wi10 = tWih1[G * 2 + 0], wi11 = tWih1[G * 2 + 1];
        const float wh10 = tWhh1[G * 2 + 0], wh11 = tWhh1[G * 2 + 1];
        const float bT1 = tbih1[G] + tbhh1[G];
        const bool isg = ((G >> 1) == 2);      // g-gate type
        const float zm = isg ? 2.f : 1.f, sm = isg ? 2.f : 1.f, sa = isg ? -1.f : 0.f;
        // states: wave-uniform replicated registers
        float ht00 = 0.f, ht01 = 0.f, ct00 = 0.f, ct01 = 0.f;
        float ht10 = 0.f, ht11 = 0.f, ct10 = 0.f, ct11 = 0.f;

        // depth-3 register prefetch: entering iter i, xa=x(i+1), xb=x(i+2), xc=x(i+3)
        float xa[4] = {0,0,0,0}, xb[4] = {0,0,0,0}, xc[4] = {0,0,0,0};
        if (l < 16) {
            float x0[4];
            loadx4(x0, x_r, x_t, xr_base, xt_base, l);
#pragma unroll
            for (int u = 0; u < 4; ++u) {
                int v = l + 16 * u;
                if (v < 49) { in0[0][v] = x0[u]; tring[0][v] = x0[u]; }
            }
            loadx4(xa, x_r, x_t, xr_base + 47,     xt_base + 2,     l);
            loadx4(xb, x_r, x_t, xr_base + 2 * 47, xt_base + 2 * 2, l);
            loadx4(xc, x_r, x_t, xr_base + 3 * 47, xt_base + 3 * 2, l);
        }
        __syncthreads();   // pre-loop (pairs with A/B pre-loop)

        for (int i = 0; i <= T_STEPS + 1; ++i) {
            const int nxt = (i & 1) ^ 1;
            if (i >= 2) {
                // t0 gates, step tau=i-2; input = tring[tau&3] = [x(tau)(49)|hr1(tau)(47)]
                const float4* tin = reinterpret_cast<const float4*>(tring[(i - 2) & 3]) + 6 * p;
                f2 b0 = {0,0}, b1 = {0,0};
#pragma unroll
                for (int u = 0; u < 6; ++u) {
                    float4 v = tin[u];
                    b0 = __builtin_elementwise_fma(wT[2*u],   f2{v.x, v.y}, b0);
                    b1 = __builtin_elementwise_fma(wT[2*u+1], f2{v.z, v.w}, b1);
                }
                f2 bs = b0 + b1;
                float acc = bs.x + bs.y;
                acc += dppf<DPP_XOR1>(acc);
                acc += dppf<DPP_XOR2>(acc);
                float pre0 = acc + bT0 + wh00 * ht00 + wh01 * ht01;
                float a0 = gate_act(pre0, zm, sm, sa);
                // broadcast the 8 gate acts as wave-uniform scalars; update cells replicated
                float i0 = rlane(a0, 0),  i1 = rlane(a0, 4);
                float f0 = rlane(a0, 8),  f1 = rlane(a0, 12);
                float g0 = rlane(a0, 16), g1 = rlane(a0, 20);
                float o0 = rlane(a0, 24), o1 = rlane(a0, 28);
                ct00 = fmaf(f0, ct00, i0 * g0);
                ct01 = fmaf(f1, ct01, i1 * g1);
                ht00 = o0 * tanh_f(ct00);
                ht01 = o1 * tanh_f(ct01);
                // layer-1: per-lane gate G, uniform inputs
                float pre1 = bT1 + wi10 * ht00 + wi11 * ht01 + wh10 * ht10 + wh11 * ht11;
                float a1 = gate_act(pre1, zm, sm, sa);
                float ji0 = rlane(a1, 0),  ji1 = rlane(a1, 4);
                float jf0 = rlane(a1, 8),  jf1 = rlane(a1, 12);
                float jg0 = rlane(a1, 16), jg1 = rlane(a1, 20);
                float jo0 = rlane(a1, 24), jo1 = rlane(a1, 28);
                ct10 = fmaf(jf0, ct10, ji0 * jg0);
                ct11 = fmaf(jf1, ct11, ji1 * jg1);
                ht10 = jo0 * tanh_f(ct10);
                ht11 = jo1 * tanh_f(ct11);
                if (l < 2) t_out[((size_t)b * T_STEPS + (i - 2)) * 2 + l] = (l == 0) ? ht10 : ht11;
            }
            // staging: publish x(i+1) (in regs) then issue loads for x(i+4)
            if (l < 16) {
                const int tw = i + 1;
                if (tw < T_STEPS) {
#pragma unroll
                    for (int u = 0; u < 4; ++u) {
                        int v = l + 16 * u;
                        if (v < 49) { in0[nxt][v] = xa[u]; tring[tw & 3][v] = xa[u]; }
                    }
                }
#pragma unroll
                for (int u = 0; u < 4; ++u) { xa[u] = xb[u]; xb[u] = xc[u]; }
                int tl = i + 4;
                if (tl > T_STEPS - 1) tl = T_STEPS - 1;
                loadx4(xc, x_r, x_t, xr_base + (size_t)tl * 47, xt_base + (size_t)tl * 2, l);
            }
            __syncthreads();
        }
    }
}

extern "C" void kernel_launch(void* const* d_in, const int* in_sizes, int n_in,
                              void* d_out, int out_size, void* d_ws, size_t ws_size,
                              hipStream_t stream) {
    const float* x_r   = (const float*)d_in[0];
    const float* x_t   = (const float*)d_in[1];
    const float* rWih0 = (const float*)d_in[2];
    const float* rWhh0 = (const float*)d_in[3];
    const float* rbih0 = (const float*)d_in[4];
    const float* rbhh0 = (const float*)d_in[5];
    const float* rWih1 = (const float*)d_in[6];
    const float* rWhh1 = (const float*)d_in[7];
    const float* rbih1 = (const float*)d_in[8];
    const float* rbhh1 = (const float*)d_in[9];
    const float* tWih0 = (const float*)d_in[10];
    const float* tWhh0 = (const float*)d_in[11];
    const float* tbih0 = (const float*)d_in[12];
    const float* tbhh0 = (const float*)d_in[13];
    const float* tWih1 = (const float*)d_in[14];
    const float* tWhh1 = (const float*)d_in[15];
    const float* tbih1 = (const float*)d_in[16];
    const float* tbhh1 = (const float*)d_in[17];

    float* r_out = (float*)d_out;
    float* t_out = r_out + (size_t)256 * T_STEPS * 47;

    hipLaunchKernelGGL(adrnn_fused, dim3(256), dim3(448), 0, stream,
                       x_r, x_t, rWih0, rWhh0, rbih0, rbhh0, rWih1, rWhh1, rbih1, rbhh1,
                       tWih0, tWhh0, tbih0, tbhh0, tWih1, tWhh1, tbih1, tbhh1,
                       r_out, t_out);
}

// Round 7
// 1719.184 us; speedup vs baseline: 1.2998x; 1.0923x over previous
//
#include <hip/hip_runtime.h>

#define T_STEPS 2048

typedef float f2 __attribute__((ext_vector_type(2)));

__device__ __forceinline__ float fast_rcp(float x) { return __builtin_amdgcn_rcpf(x); }

// sigmoid(x): zm=1,sm=1,sa=0 ; tanh(x)=2*sigmoid(2x)-1: zm=2,sm=2,sa=-1
__device__ __forceinline__ float gate_act(float x, float zm, float sm, float sa) {
    float e = __expf(-x * zm);
    return fmaf(fast_rcp(1.0f + e), sm, sa);
}

__device__ __forceinline__ float tanh_f(float c) {
    float e = __expf(-2.0f * c);
    return fmaf(2.0f, fast_rcp(1.0f + e), -1.0f);
}

// Barrier that drains ONLY the LDS counter (lgkmcnt) — NOT vmcnt.
// __syncthreads() would emit s_waitcnt vmcnt(0) before s_barrier, which
// synchronously waits every iteration for in-flight global prefetch loads
// and output stores (~300-900cy HBM/L2 round trip) — the fixed ~2200cy/step
// cost seen in rounds 1-6. LDS visibility (h, x staging) only needs lgkmcnt.
#define LDS_BARRIER() asm volatile("s_waitcnt lgkmcnt(0)\n\ts_barrier" ::: "memory")

// DPP quad_perm cross-lane (register-file permute, ~4cy)
#define DPP_XOR1 0xB1   // quad_perm [1,0,3,2]
#define DPP_XOR2 0x4E   // quad_perm [2,3,0,1]
#define DPP_XOR3 0x1B   // quad_perm [3,2,1,0]

template<int CTRL>
__device__ __forceinline__ float dppf(float x) {
    int r = __builtin_amdgcn_update_dpp(0, __builtin_bit_cast(int, x), CTRL, 0xF, 0xF, true);
    return __builtin_bit_cast(float, r);
}

__device__ __forceinline__ float rlane(float x, int lane) {
    return __builtin_bit_cast(float, __builtin_amdgcn_readlane(__builtin_bit_cast(int, x), lane));
}

__device__ __forceinline__ void loadx4(float (&dst)[4], const float* __restrict__ x_r,
                                       const float* __restrict__ x_t,
                                       size_t xrb, size_t xtb, int l) {
#pragma unroll
    for (int u = 0; u < 4; ++u) {
        int v = l + 16 * u;
        dst[u] = (v < 47) ? x_r[xrb + v] : ((v < 49) ? x_t[xtb + (v - 47)] : 0.0f);
    }
}

__global__ __launch_bounds__(448, 1) void adrnn_fused(
    const float* __restrict__ x_r, const float* __restrict__ x_t,
    const float* __restrict__ rWih0, const float* __restrict__ rWhh0,
    const float* __restrict__ rbih0, const float* __restrict__ rbhh0,
    const float* __restrict__ rWih1, const float* __restrict__ rWhh1,
    const float* __restrict__ rbih1, const float* __restrict__ rbhh1,
    const float* __restrict__ tWih0, const float* __restrict__ tWhh0,
    const float* __restrict__ tbih0, const float* __restrict__ tbhh0,
    const float* __restrict__ tWih1, const float* __restrict__ tWhh1,
    const float* __restrict__ tbih1, const float* __restrict__ tbhh1,
    float* __restrict__ r_out, float* __restrict__ t_out)
{
    // ping-pong input vectors; iter i reads buf[i&1], writes buf[(i+1)&1]
    __shared__ __align__(16) float in0[2][96];    // [x_r(47)|x_t(2)|hr0(47)]
    __shared__ __align__(16) float in1[2][96];    // [hr0(47)|pad|hr1(47)|pad]
    __shared__ __align__(16) float tring[4][96];  // slot tau&3: [x(tau)(49)|hr1(tau)(47)]

    const int tid = threadIdx.x;
    const int b = blockIdx.x;
    const size_t xr_base = (size_t)b * T_STEPS * 47;
    const size_t xt_base = (size_t)b * T_STEPS * 2;

    if (tid < 96) {
        in1[0][tid] = 0.0f; in1[1][tid] = 0.0f;
        if (tid >= 49) { in0[0][tid] = 0.0f; in0[1][tid] = 0.0f; }
    }

    if (tid < 384) {
        // ===== A group (waves 0-2): layer-0 step i. B group (waves 3-5): layer-1 step i-1.
        // lane (jj, q): quarter-q partial dot (24 elems) for ALL 4 gates of unit jj.
        const bool isA = (tid < 192);
        const int t0 = isA ? tid : tid - 192;
        const int jj = t0 >> 2, q = t0 & 3;
        const bool act_lane = (jj < 47);

        f2 w[4][12];
#pragma unroll
        for (int g = 0; g < 4; ++g)
#pragma unroll
            for (int u = 0; u < 12; ++u) w[g][u] = f2{0.0f, 0.0f};
        float bias = 0.0f;
        if (act_lane) {
            if (isA) {
#pragma unroll
                for (int g = 0; g < 4; ++g) {
                    const int rg = g * 47 + jj;
#pragma unroll
                    for (int u = 0; u < 12; ++u) {
                        int c0 = 24 * q + 2 * u, c1 = c0 + 1;
                        float w0 = (c0 < 49) ? rWih0[rg * 49 + c0] : rWhh0[rg * 47 + (c0 - 49)];
                        float w1 = (c1 < 49) ? rWih0[rg * 49 + c1] : rWhh0[rg * 47 + (c1 - 49)];
                        w[g][u] = f2{w0, w1};
                    }
                }
                bias = rbih0[q * 47 + jj] + rbhh0[q * 47 + jj];
            } else {
#pragma unroll
                for (int g = 0; g < 4; ++g) {
                    const int rg = g * 47 + jj;
#pragma unroll
                    for (int u = 0; u < 12; ++u) {
                        int c0 = 24 * q + 2 * u, c1 = c0 + 1;
                        float w0 = 0.0f, w1 = 0.0f;
                        if (c0 < 47) w0 = rWih1[rg * 47 + c0];
                        else if (c0 >= 48 && c0 < 95) w0 = rWhh1[rg * 47 + (c0 - 48)];
                        if (c1 < 47) w1 = rWih1[rg * 47 + c1];
                        else if (c1 >= 48 && c1 < 95) w1 = rWhh1[rg * 47 + (c1 - 48)];
                        w[g][u] = f2{w0, w1};
                    }
                }
                bias = rbih1[q * 47 + jj] + rbhh1[q * 47 + jj];
            }
        }
        // this lane activates gate q (0=i,1=f,2=g,3=o)
        const float zm = (q == 2) ? 2.0f : 1.0f;
        const float sm = (q == 2) ? 2.0f : 1.0f;
        const float sa = (q == 2) ? -1.0f : 0.0f;
        const bool wr = (q == 0) && act_lane;
        float c = 0.0f;

        __syncthreads();   // pre-loop: full drain once is fine

        for (int i = 0; i <= T_STEPS + 1; ++i) {
            const int cur = i & 1, nxt = cur ^ 1;
            const bool on = isA ? (i < T_STEPS) : (i >= 1 && i <= T_STEPS);
            if (on) {
                const float4* v4 = reinterpret_cast<const float4*>(isA ? in0[cur] : in1[cur]) + 6 * q;
                f2 a00 = {0,0}, a01 = {0,0}, a10 = {0,0}, a11 = {0,0};
                f2 a20 = {0,0}, a21 = {0,0}, a30 = {0,0}, a31 = {0,0};
#pragma unroll
                for (int u = 0; u < 6; ++u) {
                    float4 v = v4[u];
                    f2 lo = f2{v.x, v.y}, hi = f2{v.z, v.w};
                    a00 = __builtin_elementwise_fma(w[0][2*u],   lo, a00);
                    a01 = __builtin_elementwise_fma(w[0][2*u+1], hi, a01);
                    a10 = __builtin_elementwise_fma(w[1][2*u],   lo, a10);
                    a11 = __builtin_elementwise_fma(w[1][2*u+1], hi, a11);
                    a20 = __builtin_elementwise_fma(w[2][2*u],   lo, a20);
                    a21 = __builtin_elementwise_fma(w[2][2*u+1], hi, a21);
                    a30 = __builtin_elementwise_fma(w[3][2*u],   lo, a30);
                    a31 = __builtin_elementwise_fma(w[3][2*u+1], hi, a31);
                }
                f2 s0 = a00 + a01, s1 = a10 + a11, s2 = a20 + a21, s3 = a30 + a31;
                float P0 = s0.x + s0.y, P1 = s1.x + s1.y, P2 = s2.x + s2.y, P3 = s3.x + s3.y;
                // DPP butterfly across the 4 quarter-lanes (register permute, no LDS pipe)
                P0 += dppf<DPP_XOR1>(P0); P1 += dppf<DPP_XOR1>(P1);
                P2 += dppf<DPP_XOR1>(P2); P3 += dppf<DPP_XOR1>(P3);
                P0 += dppf<DPP_XOR2>(P0); P1 += dppf<DPP_XOR2>(P1);
                P2 += dppf<DPP_XOR2>(P2); P3 += dppf<DPP_XOR2>(P3);
                float pre = (q & 2) ? ((q & 1) ? P3 : P2) : ((q & 1) ? P1 : P0);
                pre += bias;
                float av = gate_act(pre, zm, sm, sa);
                // gather i,f,g,o within the quad via DPP
                float fv = dppf<DPP_XOR1>(av);
                float gv = dppf<DPP_XOR2>(av);
                float ov = dppf<DPP_XOR3>(av);
                if (wr) {
                    c = fmaf(fv, c, av * gv);
                    float h = ov * tanh_f(c);
                    if (isA) {
                        in0[nxt][49 + jj] = h;
                        in1[nxt][jj] = h;
                    } else {
                        in1[nxt][48 + jj] = h;
                        tring[(i - 1) & 3][49 + jj] = h;   // hr1(i-1) for the t-RNN
                        r_out[((size_t)b * T_STEPS + (i - 1)) * 47 + jj] = h;
                    }
                }
            }
            LDS_BARRIER();
        }
    } else {
        // ===== T wave (wave 6): t-RNN step i-2 (zero bpermutes) + x staging =====
        const int l = tid - 384;
        const int G = (l >> 2) & 7;            // gate index: type*2+unit (lanes 32-63 replicate)
        const int p = l & 3;                   // quarter of the 96-elem input
        // layer-0 weights: quarter-p slice (24 elems) of row G
        f2 wT[12];
#pragma unroll
        for (int u = 0; u < 12; ++u)
            wT[u] = f2{tWih0[G * 96 + p * 24 + 2 * u], tWih0[G * 96 + p * 24 + 2 * u + 1]};
        const float bT0 = tbih0[G] + tbhh0[G];
        const float wh00 = tWhh0[G * 2 + 0], wh01 = tWhh0[G * 2 + 1];
        const float wi10 = tWih1[G * 2 + 0], wi11 = tWih1[G * 2 + 1];
        const float wh10 = tWhh1[G * 2 + 0], wh11 = tWhh1[G * 2 + 1];
        const float bT1 = tbih1[G] + tbhh1[G];
        const bool isg = ((G >> 1) == 2);      // g-gate type
        const float zm = isg ? 2.f : 1.f, sm = isg ? 2.f : 1.f, sa = isg ? -1.f : 0.f;
        // states: wave-uniform replicated registers
        float ht00 = 0.f, ht01 = 0.f, ct00 = 0.f, ct01 = 0.f;
        float ht10 = 0.f, ht11 = 0.f, ct10 = 0.f, ct11 = 0.f;

        // depth-3 register prefetch: entering iter i, xa=x(i+1), xb=x(i+2), xc=x(i+3)
        float xa[4] = {0,0,0,0}, xb[4] = {0,0,0,0}, xc[4] = {0,0,0,0};
        if (l < 16) {
            float x0[4];
            loadx4(x0, x_r, x_t, xr_base, xt_base, l);
#pragma unroll
            for (int u = 0; u < 4; ++u) {
                int v = l + 16 * u;
                if (v < 49) { in0[0][v] = x0[u]; tring[0][v] = x0[u]; }
            }
            loadx4(xa, x_r, x_t, xr_base + 47,     xt_base + 2,     l);
            loadx4(xb, x_r, x_t, xr_base + 2 * 47, xt_base + 2 * 2, l);
            loadx4(xc, x_r, x_t, xr_base + 3 * 47, xt_base + 3 * 2, l);
        }
        __syncthreads();   // pre-loop (pairs with A/B pre-loop)

        for (int i = 0; i <= T_STEPS + 1; ++i) {
            const int nxt = (i & 1) ^ 1;
            if (i >= 2) {
                // t0 gates, step tau=i-2; input = tring[tau&3] = [x(tau)(49)|hr1(tau)(47)]
                const float4* tin = reinterpret_cast<const float4*>(tring[(i - 2) & 3]) + 6 * p;
                f2 b0 = {0,0}, b1 = {0,0};
#pragma unroll
                for (int u = 0; u < 6; ++u) {
                    float4 v = tin[u];
                    b0 = __builtin_elementwise_fma(wT[2*u],   f2{v.x, v.y}, b0);
                    b1 = __builtin_elementwise_fma(wT[2*u+1], f2{v.z, v.w}, b1);
                }
                f2 bs = b0 + b1;
                float acc = bs.x + bs.y;
                acc += dppf<DPP_XOR1>(acc);
                acc += dppf<DPP_XOR2>(acc);
                float pre0 = acc + bT0 + wh00 * ht00 + wh01 * ht01;
                float a0 = gate_act(pre0, zm, sm, sa);
                // broadcast the 8 gate acts as wave-uniform scalars; update cells replicated
                float i0 = rlane(a0, 0),  i1 = rlane(a0, 4);
                float f0 = rlane(a0, 8),  f1 = rlane(a0, 12);
                float g0 = rlane(a0, 16), g1 = rlane(a0, 20);
                float o0 = rlane(a0, 24), o1 = rlane(a0, 28);
                ct00 = fmaf(f0, ct00, i0 * g0);
                ct01 = fmaf(f1, ct01, i1 * g1);
                ht00 = o0 * tanh_f(ct00);
                ht01 = o1 * tanh_f(ct01);
                // layer-1: per-lane gate G, uniform inputs
                float pre1 = bT1 + wi10 * ht00 + wi11 * ht01 + wh10 * ht10 + wh11 * ht11;
                float a1 = gate_act(pre1, zm, sm, sa);
                float ji0 = rlane(a1, 0),  ji1 = rlane(a1, 4);
                float jf0 = rlane(a1, 8),  jf1 = rlane(a1, 12);
                float jg0 = rlane(a1, 16), jg1 = rlane(a1, 20);
                float jo0 = rlane(a1, 24), jo1 = rlane(a1, 28);
                ct10 = fmaf(jf0, ct10, ji0 * jg0);
                ct11 = fmaf(jf1, ct11, ji1 * jg1);
                ht10 = jo0 * tanh_f(ct10);
                ht11 = jo1 * tanh_f(ct11);
                if (l < 2) t_out[((size_t)b * T_STEPS + (i - 2)) * 2 + l] = (l == 0) ? ht10 : ht11;
            }
            // staging: publish x(i+1) (in regs) then issue loads for x(i+4)
            if (l < 16) {
                const int tw = i + 1;
                if (tw < T_STEPS) {
#pragma unroll
                    for (int u = 0; u < 4; ++u) {
                        int v = l + 16 * u;
                        if (v < 49) { in0[nxt][v] = xa[u]; tring[tw & 3][v] = xa[u]; }
                    }
                }
#pragma unroll
                for (int u = 0; u < 4; ++u) { xa[u] = xb[u]; xb[u] = xc[u]; }
                int tl = i + 4;
                if (tl > T_STEPS - 1) tl = T_STEPS - 1;
                loadx4(xc, x_r, x_t, xr_base + (size_t)tl * 47, xt_base + (size_t)tl * 2, l);
            }
            LDS_BARRIER();
        }
    }
}

extern "C" void kernel_launch(void* const* d_in, const int* in_sizes, int n_in,
                              void* d_out, int out_size, void* d_ws, size_t ws_size,
                              hipStream_t stream) {
    const float* x_r   = (const float*)d_in[0];
    const float* x_t   = (const float*)d_in[1];
    const float* rWih0 = (const float*)d_in[2];
    const float* rWhh0 = (const float*)d_in[3];
    const float* rbih0 = (const float*)d_in[4];
    const float* rbhh0 = (const float*)d_in[5];
    const float* rWih1 = (const float*)d_in[6];
    const float* rWhh1 = (const float*)d_in[7];
    const float* rbih1 = (const float*)d_in[8];
    const float* rbhh1 = (const float*)d_in[9];
    const float* tWih0 = (const float*)d_in[10];
    const float* tWhh0 = (const float*)d_in[11];
    const float* tbih0 = (const float*)d_in[12];
    const float* tbhh0 = (const float*)d_in[13];
    const float* tWih1 = (const float*)d_in[14];
    const float* tWhh1 = (const float*)d_in[15];
    const float* tbih1 = (const float*)d_in[16];
    const float* tbhh1 = (const float*)d_in[17];

    float* r_out = (float*)d_out;
    float* t_out = r_out + (size_t)256 * T_STEPS * 47;

    hipLaunchKernelGGL(adrnn_fused, dim3(256), dim3(448), 0, stream,
                       x_r, x_t, rWih0, rWhh0, rbih0, rbhh0, rWih1, rWhh1, rbih1, rbhh1,
                       tWih0, tWhh0, tbih0, tbhh0, tWih1, tWhh1, tbih1, tbhh1,
                       r_out, t_out);
}

// Round 8
// 1618.149 us; speedup vs baseline: 1.3809x; 1.0624x over previous
//
#include <hip/hip_runtime.h>

#define T_STEPS 2048

typedef float f2 __attribute__((ext_vector_type(2)));

__device__ __forceinline__ float fast_rcp(float x) { return __builtin_amdgcn_rcpf(x); }

// sigmoid(x): zm=1,sm=1,sa=0 ; tanh(x)=2*sigmoid(2x)-1: zm=2,sm=2,sa=-1
__device__ __forceinline__ float gate_act(float x, float zm, float sm, float sa) {
    float e = __expf(-x * zm);
    return fmaf(fast_rcp(1.0f + e), sm, sa);
}

__device__ __forceinline__ float tanh_f(float c) {
    float e = __expf(-2.0f * c);
    return fmaf(2.0f, fast_rcp(1.0f + e), -1.0f);
}

// Barrier that drains ONLY the LDS counter (lgkmcnt) — NOT vmcnt.
#define LDS_BARRIER() asm volatile("s_waitcnt lgkmcnt(0)\n\ts_barrier" ::: "memory")

// DPP controls
#define DPP_XOR1   0xB1    // quad_perm [1,0,3,2]
#define DPP_XOR2   0x4E    // quad_perm [2,3,0,1]
#define DPP_XOR3   0x1B    // quad_perm [3,2,1,0]
#define DPP_BCAST0 0x00    // quad_perm [0,0,0,0]
#define DPP_BCAST1 0x55    // quad_perm [1,1,1,1]
#define DPP_BCAST2 0xAA    // quad_perm [2,2,2,2]
#define DPP_BCAST3 0xFF    // quad_perm [3,3,3,3]
#define DPP_ROR4   0x124   // row rotate by 4 (quads alternate units -> direction-neutral)
#define DPP_ROR8   0x128   // row rotate by 8 (halves swap -> direction-neutral)

template<int CTRL>
__device__ __forceinline__ float dppf(float x) {
    int r = __builtin_amdgcn_update_dpp(0, __builtin_bit_cast(int, x), CTRL, 0xF, 0xF, true);
    return __builtin_bit_cast(float, r);
}

__device__ __forceinline__ void loadx4(float (&dst)[4], const float* __restrict__ x_r,
                                       const float* __restrict__ x_t,
                                       size_t xrb, size_t xtb, int l) {
#pragma unroll
    for (int u = 0; u < 4; ++u) {
        int v = l + 16 * u;
        dst[u] = (v < 47) ? x_r[xrb + v] : ((v < 49) ? x_t[xtb + (v - 47)] : 0.0f);
    }
}

__global__ __launch_bounds__(448, 1) void adrnn_fused(
    const float* __restrict__ x_r, const float* __restrict__ x_t,
    const float* __restrict__ rWih0, const float* __restrict__ rWhh0,
    const float* __restrict__ rbih0, const float* __restrict__ rbhh0,
    const float* __restrict__ rWih1, const float* __restrict__ rWhh1,
    const float* __restrict__ rbih1, const float* __restrict__ rbhh1,
    const float* __restrict__ tWih0, const float* __restrict__ tWhh0,
    const float* __restrict__ tbih0, const float* __restrict__ tbhh0,
    const float* __restrict__ tWih1, const float* __restrict__ tWhh1,
    const float* __restrict__ tbih1, const float* __restrict__ tbhh1,
    float* __restrict__ r_out, float* __restrict__ t_out)
{
    // ping-pong input vectors; iter i reads buf[i&1], writes buf[(i+1)&1]
    __shared__ __align__(16) float in0[2][96];    // [x_r(47)|x_t(2)|hr0(47)]
    __shared__ __align__(16) float in1[2][96];    // [hr0(47)|pad|hr1(47)|pad]
    __shared__ __align__(16) float tring[4][96];  // slot tau&3: [x(tau)(49)|hr1(tau)(47)]

    const int tid = threadIdx.x;
    const int b = blockIdx.x;
    const size_t xr_base = (size_t)b * T_STEPS * 47;
    const size_t xt_base = (size_t)b * T_STEPS * 2;

    if (tid < 96) {
        in1[0][tid] = 0.0f; in1[1][tid] = 0.0f;
        if (tid >= 49) { in0[0][tid] = 0.0f; in0[1][tid] = 0.0f; }
    }

    if (tid < 384) {
        // ===== A group (waves 0-2): layer-0 step i. B group (waves 3-5): layer-1 step i-1.
        const bool isA = (tid < 192);
        const int t0 = isA ? tid : tid - 192;
        const int jj = t0 >> 2, q = t0 & 3;
        const bool act_lane = (jj < 47);

        f2 w[4][12];
#pragma unroll
        for (int g = 0; g < 4; ++g)
#pragma unroll
            for (int u = 0; u < 12; ++u) w[g][u] = f2{0.0f, 0.0f};
        float bias = 0.0f;
        if (act_lane) {
            if (isA) {
#pragma unroll
                for (int g = 0; g < 4; ++g) {
                    const int rg = g * 47 + jj;
#pragma unroll
                    for (int u = 0; u < 12; ++u) {
                        int c0 = 24 * q + 2 * u, c1 = c0 + 1;
                        float w0 = (c0 < 49) ? rWih0[rg * 49 + c0] : rWhh0[rg * 47 + (c0 - 49)];
                        float w1 = (c1 < 49) ? rWih0[rg * 49 + c1] : rWhh0[rg * 47 + (c1 - 49)];
                        w[g][u] = f2{w0, w1};
                    }
                }
                bias = rbih0[q * 47 + jj] + rbhh0[q * 47 + jj];
            } else {
#pragma unroll
                for (int g = 0; g < 4; ++g) {
                    const int rg = g * 47 + jj;
#pragma unroll
                    for (int u = 0; u < 12; ++u) {
                        int c0 = 24 * q + 2 * u, c1 = c0 + 1;
                        float w0 = 0.0f, w1 = 0.0f;
                        if (c0 < 47) w0 = rWih1[rg * 47 + c0];
                        else if (c0 >= 48 && c0 < 95) w0 = rWhh1[rg * 47 + (c0 - 48)];
                        if (c1 < 47) w1 = rWih1[rg * 47 + c1];
                        else if (c1 >= 48 && c1 < 95) w1 = rWhh1[rg * 47 + (c1 - 48)];
                        w[g][u] = f2{w0, w1};
                    }
                }
                bias = rbih1[q * 47 + jj] + rbhh1[q * 47 + jj];
            }
        }
        const float zm = (q == 2) ? 2.0f : 1.0f;
        const float sm = (q == 2) ? 2.0f : 1.0f;
        const float sa = (q == 2) ? -1.0f : 0.0f;
        const bool wr = (q == 0) && act_lane;
        float c = 0.0f;

        __syncthreads();   // pre-loop: full drain once is fine

        for (int i = 0; i <= T_STEPS + 1; ++i) {
            const int cur = i & 1, nxt = cur ^ 1;
            const bool on = isA ? (i < T_STEPS) : (i >= 1 && i <= T_STEPS);
            if (on) {
                const float4* v4 = reinterpret_cast<const float4*>(isA ? in0[cur] : in1[cur]) + 6 * q;
                f2 a00 = {0,0}, a01 = {0,0}, a10 = {0,0}, a11 = {0,0};
                f2 a20 = {0,0}, a21 = {0,0}, a30 = {0,0}, a31 = {0,0};
#pragma unroll
                for (int u = 0; u < 6; ++u) {
                    float4 v = v4[u];
                    f2 lo = f2{v.x, v.y}, hi = f2{v.z, v.w};
                    a00 = __builtin_elementwise_fma(w[0][2*u],   lo, a00);
                    a01 = __builtin_elementwise_fma(w[0][2*u+1], hi, a01);
                    a10 = __builtin_elementwise_fma(w[1][2*u],   lo, a10);
                    a11 = __builtin_elementwise_fma(w[1][2*u+1], hi, a11);
                    a20 = __builtin_elementwise_fma(w[2][2*u],   lo, a20);
                    a21 = __builtin_elementwise_fma(w[2][2*u+1], hi, a21);
                    a30 = __builtin_elementwise_fma(w[3][2*u],   lo, a30);
                    a31 = __builtin_elementwise_fma(w[3][2*u+1], hi, a31);
                }
                f2 s0 = a00 + a01, s1 = a10 + a11, s2 = a20 + a21, s3 = a30 + a31;
                float P0 = s0.x + s0.y, P1 = s1.x + s1.y, P2 = s2.x + s2.y, P3 = s3.x + s3.y;
                P0 += dppf<DPP_XOR1>(P0); P1 += dppf<DPP_XOR1>(P1);
                P2 += dppf<DPP_XOR1>(P2); P3 += dppf<DPP_XOR1>(P3);
                P0 += dppf<DPP_XOR2>(P0); P1 += dppf<DPP_XOR2>(P1);
                P2 += dppf<DPP_XOR2>(P2); P3 += dppf<DPP_XOR2>(P3);
                float pre = (q & 2) ? ((q & 1) ? P3 : P2) : ((q & 1) ? P1 : P0);
                pre += bias;
                float av = gate_act(pre, zm, sm, sa);
                float fv = dppf<DPP_XOR1>(av);
                float gv = dppf<DPP_XOR2>(av);
                float ov = dppf<DPP_XOR3>(av);
                if (wr) {
                    c = fmaf(fv, c, av * gv);
                    float h = ov * tanh_f(c);
                    if (isA) {
                        in0[nxt][49 + jj] = h;
                        in1[nxt][jj] = h;
                    } else {
                        in1[nxt][48 + jj] = h;
                        tring[(i - 1) & 3][49 + jj] = h;   // hr1(i-1) for the t-RNN
                        r_out[((size_t)b * T_STEPS + (i - 1)) * 47 + jj] = h;
                    }
                }
            }
            LDS_BARRIER();
        }
    } else {
        // ===== T wave (wave 6): t-RNN step i-2, zero readlanes/bpermutes =====
        // lane l: unit u=(l>>2)&1, gate g=l&3, half hf=(l>>3)&1; rows replicate every 16.
        const int l = tid - 384;
        const int u = (l >> 2) & 1;
        const int g = l & 3;
        const int hf = (l >> 3) & 1;
        const int R0 = g * 2 + u;              // PyTorch row: gate_type*2 + unit
        // layer-0 weights: this lane's half (48 elems) of row R0
        f2 w0[24];
#pragma unroll
        for (int k = 0; k < 24; ++k)
            w0[k] = f2{tWih0[R0 * 96 + hf * 48 + 2 * k], tWih0[R0 * 96 + hf * 48 + 2 * k + 1]};
        const float bT0 = tbih0[R0] + tbhh0[R0];
        const float wh00 = tWhh0[R0 * 2 + 0], wh01 = tWhh0[R0 * 2 + 1];
        const float wi10 = tWih1[R0 * 2 + 0], wi11 = tWih1[R0 * 2 + 1];
        const float wh10 = tWhh1[R0 * 2 + 0], wh11 = tWhh1[R0 * 2 + 1];
        const float bT1 = tbih1[R0] + tbhh1[R0];
        const bool isg = (g == 2);
        const float zm = isg ? 2.f : 1.f, sm = isg ? 2.f : 1.f, sa = isg ? -1.f : 0.f;
        // replicated states
        float ht00 = 0.f, ht01 = 0.f, ct0u = 0.f;
        float ht10 = 0.f, ht11 = 0.f, ct1u = 0.f;

        // depth-3 register prefetch: entering iter i, xa=x(i+1), xb=x(i+2), xc=x(i+3)
        float xa[4] = {0,0,0,0}, xb[4] = {0,0,0,0}, xc[4] = {0,0,0,0};
        if (l < 16) {
            float x0[4];
            loadx4(x0, x_r, x_t, xr_base, xt_base, l);
#pragma unroll
            for (int uu = 0; uu < 4; ++uu) {
                int v = l + 16 * uu;
                if (v < 49) { in0[0][v] = x0[uu]; tring[0][v] = x0[uu]; }
            }
            loadx4(xa, x_r, x_t, xr_base + 47,     xt_base + 2,     l);
            loadx4(xb, x_r, x_t, xr_base + 2 * 47, xt_base + 2 * 2, l);
            loadx4(xc, x_r, x_t, xr_base + 3 * 47, xt_base + 3 * 2, l);
        }
        __syncthreads();   // pre-loop (pairs with A/B pre-loop)

        for (int i = 0; i <= T_STEPS + 1; ++i) {
            const int nxt = (i & 1) ^ 1;
            // staging FIRST so its ds_writes aren't serialized behind the t-chain
            if (l < 16) {
                const int tw = i + 1;
                if (tw < T_STEPS) {
#pragma unroll
                    for (int uu = 0; uu < 4; ++uu) {
                        int v = l + 16 * uu;
                        if (v < 49) { in0[nxt][v] = xa[uu]; tring[tw & 3][v] = xa[uu]; }
                    }
                }
#pragma unroll
                for (int uu = 0; uu < 4; ++uu) { xa[uu] = xb[uu]; xb[uu] = xc[uu]; }
                int tl = i + 4;
                if (tl > T_STEPS - 1) tl = T_STEPS - 1;
                loadx4(xc, x_r, x_t, xr_base + (size_t)tl * 47, xt_base + (size_t)tl * 2, l);
            }
            if (i >= 2) {
                // t0 gates, step tau=i-2; input = tring[tau&3] = [x(tau)(49)|hr1(tau)(47)]
                const float4* tin = reinterpret_cast<const float4*>(tring[(i - 2) & 3]) + 12 * hf;
                f2 a0v = {0,0}, a1v = {0,0}, a2v = {0,0}, a3v = {0,0};
#pragma unroll
                for (int k2 = 0; k2 < 12; k2 += 2) {
                    float4 v0 = tin[k2], v1 = tin[k2 + 1];
                    a0v = __builtin_elementwise_fma(w0[2*k2],   f2{v0.x, v0.y}, a0v);
                    a1v = __builtin_elementwise_fma(w0[2*k2+1], f2{v0.z, v0.w}, a1v);
                    a2v = __builtin_elementwise_fma(w0[2*k2+2], f2{v1.x, v1.y}, a2v);
                    a3v = __builtin_elementwise_fma(w0[2*k2+3], f2{v1.z, v1.w}, a3v);
                }
                f2 sv = (a0v + a2v) + (a1v + a3v);
                float part = sv.x + sv.y;
                float pre0 = part + dppf<DPP_ROR8>(part);   // combine half-dots
                pre0 += bT0 + wh00 * ht00 + wh01 * ht01;
                float a0 = gate_act(pre0, zm, sm, sa);
                // quad broadcasts: all lanes get i,f,g,o of their unit
                float i0 = dppf<DPP_BCAST0>(a0);
                float f0 = dppf<DPP_BCAST1>(a0);
                float g0 = dppf<DPP_BCAST2>(a0);
                float o0 = dppf<DPP_BCAST3>(a0);
                ct0u = fmaf(f0, ct0u, i0 * g0);
                float htu = o0 * tanh_f(ct0u);
                float hto = dppf<DPP_ROR4>(htu);            // other unit's h
                ht00 = (u == 0) ? htu : hto;
                ht01 = (u == 0) ? hto : htu;
                // layer 1
                float pre1 = bT1 + wi10 * ht00 + wi11 * ht01 + wh10 * ht10 + wh11 * ht11;
                float a1 = gate_act(pre1, zm, sm, sa);
                float ji = dppf<DPP_BCAST0>(a1);
                float jf = dppf<DPP_BCAST1>(a1);
                float jg = dppf<DPP_BCAST2>(a1);
                float jo = dppf<DPP_BCAST3>(a1);
                ct1u = fmaf(jf, ct1u, ji * jg);
                float h1u = jo * tanh_f(ct1u);
                float h1o = dppf<DPP_ROR4>(h1u);
                ht10 = (u == 0) ? h1u : h1o;
                ht11 = (u == 0) ? h1o : h1u;
                if (l == 0) {
                    float2 tv = {ht10, ht11};
                    *reinterpret_cast<float2*>(&t_out[((size_t)b * T_STEPS + (i - 2)) * 2]) = tv;
                }
            }
            LDS_BARRIER();
        }
    }
}

extern "C" void kernel_launch(void* const* d_in, const int* in_sizes, int n_in,
                              void* d_out, int out_size, void* d_ws, size_t ws_size,
                              hipStream_t stream) {
    const float* x_r   = (const float*)d_in[0];
    const float* x_t   = (const float*)d_in[1];
    const float* rWih0 = (const float*)d_in[2];
    const float* rWhh0 = (const float*)d_in[3];
    const float* rbih0 = (const float*)d_in[4];
    const float* rbhh0 = (const float*)d_in[5];
    const float* rWih1 = (const float*)d_in[6];
    const float* rWhh1 = (const float*)d_in[7];
    const float* rbih1 = (const float*)d_in[8];
    const float* rbhh1 = (const float*)d_in[9];
    const float* tWih0 = (const float*)d_in[10];
    const float* tWhh0 = (const float*)d_in[11];
    const float* tbih0 = (const float*)d_in[12];
    const float* tbhh0 = (const float*)d_in[13];
    const float* tWih1 = (const float*)d_in[14];
    const float* tWhh1 = (const float*)d_in[15];
    const float* tbih1 = (const float*)d_in[16];
    const float* tbhh1 = (const float*)d_in[17];

    float* r_out = (float*)d_out;
    float* t_out = r_out + (size_t)256 * T_STEPS * 47;

    hipLaunchKernelGGL(adrnn_fused, dim3(256), dim3(448), 0, stream,
                       x_r, x_t, rWih0, rWhh0, rbih0, rbhh0, rWih1, rWhh1, rbih1, rbhh1,
                       tWih0, tWhh0, tbih0, tbhh0, tWih1, tWhh1, tbih1, tbhh1,
                       r_out, t_out);
}

// Round 9
// 1443.045 us; speedup vs baseline: 1.5485x; 1.1213x over previous
//
#include <hip/hip_runtime.h>

#define T_STEPS 2048
#define TOTAL   2080   // T_STEPS + 32 (deepest lag)

typedef float f2 __attribute__((ext_vector_type(2)));

__device__ __forceinline__ float fast_rcp(float x) { return __builtin_amdgcn_rcpf(x); }

__device__ __forceinline__ float sig_f(float x) {
    return fast_rcp(1.0f + __expf(-x));
}
__device__ __forceinline__ float tanh_f(float x) {
    float e = __expf(-2.0f * x);
    return fmaf(2.0f, fast_rcp(1.0f + e), -1.0f);
}
// parametric: sigmoid zm=1,sm=1,sa=0 ; tanh = 2*sigmoid(2x)-1
__device__ __forceinline__ float gate_act(float x, float zm, float sm, float sa) {
    float e = __expf(-x * zm);
    return fmaf(fast_rcp(1.0f + e), sm, sa);
}

// Drain ONLY lgkmcnt (LDS) before barrier — never vmcnt (R7 win).
#define LDS_BARRIER() asm volatile("s_waitcnt lgkmcnt(0)\n\ts_barrier" ::: "memory")

#define DPP_BCAST0 0x00
#define DPP_BCAST1 0x55
#define DPP_BCAST2 0xAA
#define DPP_BCAST3 0xFF
#define DPP_ROR4   0x124
#define DPP_ROR8   0x128
template<int CTRL>
__device__ __forceinline__ float dppf(float x) {
    int r = __builtin_amdgcn_update_dpp(0, __builtin_bit_cast(int, x), CTRL, 0xF, 0xF, true);
    return __builtin_bit_cast(float, r);
}

__device__ __forceinline__ void loadx4(float (&dst)[4], const float* __restrict__ x_r,
                                       const float* __restrict__ x_t,
                                       size_t xrb, size_t xtb, int l) {
#pragma unroll
    for (int u = 0; u < 4; ++u) {
        int v = l + 16 * u;
        dst[u] = (v < 47) ? x_r[xrb + v] : ((v < 49) ? x_t[xtb + (v - 47)] : 0.0f);
    }
}

__device__ __forceinline__ void unpack12(f2 (&in)[24], const float4* __restrict__ r4) {
#pragma unroll
    for (int u = 0; u < 12; ++u) {
        float4 v = r4[u];
        in[2 * u]     = f2{v.x, v.y};
        in[2 * u + 1] = f2{v.z, v.w};
    }
}

__device__ __forceinline__ void dot4(float (&pre)[4], const f2 (&in)[24],
                                     const f2 (&w)[4][24], float4 init) {
    f2 a0 = f2{init.x, 0.f}, a1 = f2{init.y, 0.f}, a2 = f2{init.z, 0.f}, a3 = f2{init.w, 0.f};
#pragma unroll
    for (int u = 0; u < 24; ++u) {
        a0 = __builtin_elementwise_fma(w[0][u], in[u], a0);
        a1 = __builtin_elementwise_fma(w[1][u], in[u], a1);
        a2 = __builtin_elementwise_fma(w[2][u], in[u], a2);
        a3 = __builtin_elementwise_fma(w[3][u], in[u], a3);
    }
    pre[0] = a0.x + a0.y; pre[1] = a1.x + a1.y;
    pre[2] = a2.x + a2.y; pre[3] = a3.x + a3.y;
}

__global__ __launch_bounds__(320, 1) void adrnn_fused(
    const float* __restrict__ x_r, const float* __restrict__ x_t,
    const float* __restrict__ rWih0, const float* __restrict__ rWhh0,
    const float* __restrict__ rbih0, const float* __restrict__ rbhh0,
    const float* __restrict__ rWih1, const float* __restrict__ rWhh1,
    const float* __restrict__ rbih1, const float* __restrict__ rbhh1,
    const float* __restrict__ tWih0, const float* __restrict__ tWhh0,
    const float* __restrict__ tbih0, const float* __restrict__ tbhh0,
    const float* __restrict__ tWih1, const float* __restrict__ tWhh1,
    const float* __restrict__ tbih1, const float* __restrict__ tbhh1,
    float* __restrict__ r_out, float* __restrict__ t_out)
{
    // Rings. All cross-wave reads touch data written in a PREVIOUS 8-step group
    // (made visible by the group barrier); same-wave RAW ordered by lgkmcnt.
    __shared__ __align__(16) float tring[64][112]; // [x 0..48 | pad | h1 64..110 | pad 111]
    __shared__ __align__(16) float h0ring[16][48]; // h0(s) in slot s&15, [47]=0 pad
    __shared__ __align__(16) float pAring[16][188];// Wih0*x(s)+b0, float4 per unit
    __shared__ __align__(16) float pBring[16][188];// Wih1*h0(s)+b1

    const int tid = threadIdx.x;
    const int wid = tid >> 6;
    const int l   = tid & 63;
    const int j   = l;                    // unit index for waves 0-3
    const int b = blockIdx.x;
    const size_t xr_base = (size_t)b * T_STEPS * 47;
    const size_t xt_base = (size_t)b * T_STEPS * 2;

    // zero-init (waves 0-3) — h1 region + pads of tring, all of h0ring.
    if (tid < 256) {
        for (int k = tid; k < 64 * 48; k += 256) tring[k / 48][64 + (k % 48)] = 0.0f;
        for (int k = tid; k < 16 * 48; k += 256) h0ring[k / 48][k % 48] = 0.0f;
    }

    if (wid == 0) {
        // ===== XA: pA(i) = Wih0 * x(i) + b0  (lag 0, non-recurrent) =====
        f2 w[4][24]; float w48[4]; float4 bias = {0, 0, 0, 0};
#pragma unroll
        for (int g = 0; g < 4; ++g) { w48[g] = 0.f;
#pragma unroll
            for (int u = 0; u < 24; ++u) w[g][u] = f2{0.f, 0.f}; }
        if (j < 47) {
            float bb[4];
#pragma unroll
            for (int g = 0; g < 4; ++g) {
                const int row = g * 47 + j;
#pragma unroll
                for (int u = 0; u < 24; ++u)
                    w[g][u] = f2{rWih0[row * 49 + 2 * u], rWih0[row * 49 + 2 * u + 1]};
                w48[g] = rWih0[row * 49 + 48];
                bb[g] = rbih0[row] + rbhh0[row];
            }
            bias = {bb[0], bb[1], bb[2], bb[3]};
        }
        __syncthreads();
        for (int i = 0; i < TOTAL; ++i) {
            if (i < T_STEPS && j < 47) {
                f2 in[24];
                unpack12(in, (const float4*)&tring[i & 63][0]);
                float x48 = tring[i & 63][48];
                float pre[4];
                dot4(pre, in, w, bias);
                float4 out;
                out.x = fmaf(w48[0], x48, pre[0]);
                out.y = fmaf(w48[1], x48, pre[1]);
                out.z = fmaf(w48[2], x48, pre[2]);
                out.w = fmaf(w48[3], x48, pre[3]);
                *(float4*)&pAring[i & 15][j * 4] = out;
            }
            if ((i & 7) == 7) LDS_BARRIER();
        }
    } else if (wid == 1) {
        // ===== HA: h0(s) = cell(pA(s) + Whh0*h0(s-1))  (lag 8, recurrent) =====
        f2 w[4][24];
#pragma unroll
        for (int g = 0; g < 4; ++g)
#pragma unroll
            for (int u = 0; u < 24; ++u) w[g][u] = f2{0.f, 0.f};
        if (j < 47) {
#pragma unroll
            for (int g = 0; g < 4; ++g) {
                const int row = g * 47 + j;
#pragma unroll
                for (int u = 0; u < 23; ++u)
                    w[g][u] = f2{rWhh0[row * 47 + 2 * u], rWhh0[row * 47 + 2 * u + 1]};
                w[g][23] = f2{rWhh0[row * 47 + 46], 0.f};
            }
        }
        float c0 = 0.f;
        __syncthreads();
        for (int i = 0; i < TOTAL; ++i) {
            const int s = i - 8;
            if (s >= 0 && s < T_STEPS && j < 47) {
                float4 pa = *(const float4*)&pAring[s & 15][j * 4];
                f2 in[24];
                unpack12(in, (const float4*)&h0ring[(s - 1) & 15][0]);
                float pre[4];
                dot4(pre, in, w, pa);
                float iv = sig_f(pre[0]), fv = sig_f(pre[1]);
                float gv = tanh_f(pre[2]), ov = sig_f(pre[3]);
                c0 = fmaf(fv, c0, iv * gv);
                float h = ov * tanh_f(c0);
                h0ring[s & 15][j] = h;
            }
            if ((i & 7) == 7) LDS_BARRIER();
        }
    } else if (wid == 2) {
        // ===== XB: pB(s) = Wih1 * h0(s) + b1  (lag 16, non-recurrent) =====
        f2 w[4][24]; float4 bias = {0, 0, 0, 0};
#pragma unroll
        for (int g = 0; g < 4; ++g)
#pragma unroll
            for (int u = 0; u < 24; ++u) w[g][u] = f2{0.f, 0.f};
        if (j < 47) {
            float bb[4];
#pragma unroll
            for (int g = 0; g < 4; ++g) {
                const int row = g * 47 + j;
#pragma unroll
                for (int u = 0; u < 23; ++u)
                    w[g][u] = f2{rWih1[row * 47 + 2 * u], rWih1[row * 47 + 2 * u + 1]};
                w[g][23] = f2{rWih1[row * 47 + 46], 0.f};
                bb[g] = rbih1[row] + rbhh1[row];
            }
            bias = {bb[0], bb[1], bb[2], bb[3]};
        }
        __syncthreads();
        for (int i = 0; i < TOTAL; ++i) {
            const int s = i - 16;
            if (s >= 0 && s < T_STEPS && j < 47) {
                f2 in[24];
                unpack12(in, (const float4*)&h0ring[s & 15][0]);
                float pre[4];
                dot4(pre, in, w, bias);
                *(float4*)&pBring[s & 15][j * 4] = float4{pre[0], pre[1], pre[2], pre[3]};
            }
            if ((i & 7) == 7) LDS_BARRIER();
        }
    } else if (wid == 3) {
        // ===== HB: h1(s) = cell(pB(s) + Whh1*h1(s-1))  (lag 24, recurrent) =====
        f2 w[4][24];
#pragma unroll
        for (int g = 0; g < 4; ++g)
#pragma unroll
            for (int u = 0; u < 24; ++u) w[g][u] = f2{0.f, 0.f};
        if (j < 47) {
#pragma unroll
            for (int g = 0; g < 4; ++g) {
                const int row = g * 47 + j;
#pragma unroll
                for (int u = 0; u < 23; ++u)
                    w[g][u] = f2{rWhh1[row * 47 + 2 * u], rWhh1[row * 47 + 2 * u + 1]};
                w[g][23] = f2{rWhh1[row * 47 + 46], 0.f};
            }
        }
        float c1 = 0.f;
        __syncthreads();
        for (int i = 0; i < TOTAL; ++i) {
            const int s = i - 24;
            if (s >= 0 && s < T_STEPS && j < 47) {
                float4 pb = *(const float4*)&pBring[s & 15][j * 4];
                f2 in[24];
                unpack12(in, (const float4*)&tring[(s - 1) & 63][64]); // h1(s-1), [111]=0
                float pre[4];
                dot4(pre, in, w, pb);
                float iv = sig_f(pre[0]), fv = sig_f(pre[1]);
                float gv = tanh_f(pre[2]), ov = sig_f(pre[3]);
                c1 = fmaf(fv, c1, iv * gv);
                float h = ov * tanh_f(c1);
                tring[s & 63][64 + j] = h;
                r_out[((size_t)b * T_STEPS + s) * 47 + j] = h;
            }
            if ((i & 7) == 7) LDS_BARRIER();
        }
    } else {
        // ===== TT: t-RNN (lag 32) + x staging (8 ahead) =====
        const int u  = (l >> 2) & 1;
        const int g  = l & 3;
        const int hf = (l >> 3) & 1;
        const int R0 = g * 2 + u;
        // hf=0: input cols 0..47 (x); hf=1: col 48 (x48, scalar) + cols 49..95 (h1, padded)
        f2 wt[24]; float wx48;
        if (hf == 0) {
            wx48 = 0.f;
#pragma unroll
            for (int k = 0; k < 24; ++k)
                wt[k] = f2{tWih0[R0 * 96 + 2 * k], tWih0[R0 * 96 + 2 * k + 1]};
        } else {
            wx48 = tWih0[R0 * 96 + 48];
#pragma unroll
            for (int k = 0; k < 23; ++k)
                wt[k] = f2{tWih0[R0 * 96 + 49 + 2 * k], tWih0[R0 * 96 + 49 + 2 * k + 1]};
            wt[23] = f2{tWih0[R0 * 96 + 95], 0.f};
        }
        const float bT0 = tbih0[R0] + tbhh0[R0];
        const float wh00 = tWhh0[R0 * 2 + 0], wh01 = tWhh0[R0 * 2 + 1];
        const float wi10 = tWih1[R0 * 2 + 0], wi11 = tWih1[R0 * 2 + 1];
        const float wh10 = tWhh1[R0 * 2 + 0], wh11 = tWhh1[R0 * 2 + 1];
        const float bT1 = tbih1[R0] + tbhh1[R0];
        const bool isg = (g == 2);
        const float zm = isg ? 2.f : 1.f, sm = isg ? 2.f : 1.f, sa = isg ? -1.f : 0.f;
        float ht00 = 0.f, ht01 = 0.f, ct0u = 0.f;
        float ht10 = 0.f, ht11 = 0.f, ct1u = 0.f;

        // prologue: stage x(0..7); prefetch regs xa=x(8), xb=x(9), xc=x(10)
        float xa[4] = {0,0,0,0}, xb[4] = {0,0,0,0}, xc[4] = {0,0,0,0};
        if (l < 16) {
            for (int t = 0; t < 8; ++t) {
                float xv[4];
                loadx4(xv, x_r, x_t, xr_base + (size_t)t * 47, xt_base + (size_t)t * 2, l);
#pragma unroll
                for (int uu = 0; uu < 4; ++uu) {
                    int v = l + 16 * uu;
                    if (v < 49) tring[t][v] = xv[uu];
                }
            }
            loadx4(xa, x_r, x_t, xr_base + (size_t)8 * 47,  xt_base + (size_t)8 * 2,  l);
            loadx4(xb, x_r, x_t, xr_base + (size_t)9 * 47,  xt_base + (size_t)9 * 2,  l);
            loadx4(xc, x_r, x_t, xr_base + (size_t)10 * 47, xt_base + (size_t)10 * 2, l);
        }
        __syncthreads();

        for (int i = 0; i < TOTAL; ++i) {
            // staging first: x(i+8) -> tring (consumed by XA next group)
            if (l < 16) {
                const int tw = i + 8;
                if (tw < T_STEPS) {
#pragma unroll
                    for (int uu = 0; uu < 4; ++uu) {
                        int v = l + 16 * uu;
                        if (v < 49) tring[tw & 63][v] = xa[uu];
                    }
                }
#pragma unroll
                for (int uu = 0; uu < 4; ++uu) { xa[uu] = xb[uu]; xb[uu] = xc[uu]; }
                int tl = i + 11;
                if (tl > T_STEPS - 1) tl = T_STEPS - 1;
                loadx4(xc, x_r, x_t, xr_base + (size_t)tl * 47, xt_base + (size_t)tl * 2, l);
            }
            const int s = i - 32;
            if (s >= 0 && s < T_STEPS) {
                f2 in[24];
                unpack12(in, (const float4*)&tring[s & 63][hf ? 64 : 0]);
                float x48 = tring[s & 63][48];
                f2 av = {0, 0}, bv = {0, 0};
#pragma unroll
                for (int k = 0; k < 12; ++k) {
                    av = __builtin_elementwise_fma(wt[2 * k],     in[2 * k],     av);
                    bv = __builtin_elementwise_fma(wt[2 * k + 1], in[2 * k + 1], bv);
                }
                f2 sv = av + bv;
                float part = fmaf(wx48, x48, sv.x + sv.y);
                float pre0 = part + dppf<DPP_ROR8>(part);
                pre0 += bT0 + wh00 * ht00 + wh01 * ht01;
                float a0 = gate_act(pre0, zm, sm, sa);
                float i0 = dppf<DPP_BCAST0>(a0);
                float f0 = dppf<DPP_BCAST1>(a0);
                float g0 = dppf<DPP_BCAST2>(a0);
                float o0 = dppf<DPP_BCAST3>(a0);
                ct0u = fmaf(f0, ct0u, i0 * g0);
                float htu = o0 * tanh_f(ct0u);
                float hto = dppf<DPP_ROR4>(htu);
                ht00 = (u == 0) ? htu : hto;
                ht01 = (u == 0) ? hto : htu;
                float pre1 = bT1 + wi10 * ht00 + wi11 * ht01 + wh10 * ht10 + wh11 * ht11;
                float a1 = gate_act(pre1, zm, sm, sa);
                float ji = dppf<DPP_BCAST0>(a1);
                float jf = dppf<DPP_BCAST1>(a1);
                float jg = dppf<DPP_BCAST2>(a1);
                float jo = dppf<DPP_BCAST3>(a1);
                ct1u = fmaf(jf, ct1u, ji * jg);
                float h1u = jo * tanh_f(ct1u);
                float h1o = dppf<DPP_ROR4>(h1u);
                ht10 = (u == 0) ? h1u : h1o;
                ht11 = (u == 0) ? h1o : h1u;
                if (l == 0) {
                    float2 tv = {ht10, ht11};
                    *reinterpret_cast<float2*>(&t_out[((size_t)b * T_STEPS + s) * 2]) = tv;
                }
            }
            if ((i & 7) == 7) LDS_BARRIER();
        }
    }
}

extern "C" void kernel_launch(void* const* d_in, const int* in_sizes, int n_in,
                              void* d_out, int out_size, void* d_ws, size_t ws_size,
                              hipStream_t stream) {
    const float* x_r   = (const float*)d_in[0];
    const float* x_t   = (const float*)d_in[1];
    const float* rWih0 = (const float*)d_in[2];
    const float* rWhh0 = (const float*)d_in[3];
    const float* rbih0 = (const float*)d_in[4];
    const float* rbhh0 = (const float*)d_in[5];
    const float* rWih1 = (const float*)d_in[6];
    const float* rWhh1 = (const float*)d_in[7];
    const float* rbih1 = (const float*)d_in[8];
    const float* rbhh1 = (const float*)d_in[9];
    const float* tWih0 = (const float*)d_in[10];
    const float* tWhh0 = (const float*)d_in[11];
    const float* tbih0 = (const float*)d_in[12];
    const float* tbhh0 = (const float*)d_in[13];
    const float* tWih1 = (const float*)d_in[14];
    const float* tWhh1 = (const float*)d_in[15];
    const float* tbih1 = (const float*)d_in[16];
    const float* tbhh1 = (const float*)d_in[17];

    float* r_out = (float*)d_out;
    float* t_out = r_out + (size_t)256 * T_STEPS * 47;

    hipLaunchKernelGGL(adrnn_fused, dim3(256), dim3(320), 0, stream,
                       x_r, x_t, rWih0, rWhh0, rbih0, rbhh0, rWih1, rWhh1, rbih1, rbhh1,
                       tWih0, tWhh0, tbih0, tbhh0, tWih1, tWhh1, tbih1, tbhh1,
                       r_out, t_out);
}